// Round 14
// baseline (186.632 us; speedup 1.0000x reference)
//
#include <hip/hip_runtime.h>
#include <hip/hip_bf16.h>
#include <math.h>

constexpr int F = 128;        // in features
constexpr int H = 64;         // out features
constexpr int NB = 32;        // nodes per gemm block
constexpr int XS_STRIDE = F + 4;
constexpr int NCH = 256;      // edge chunks (pass-A blocks) == #CUs
constexpr int SHIFT = 7;      // log2(nodes per bucket)
constexpr int BWID = 1 << SHIFT;   // 128 nodes per bucket
constexpr int MAXBUK = 512;   // >= nbuk = ceil(N/128) = 391
constexpr int CHMAX = 6400;   // >= chsz = ceil(E/NCH) = 6250

typedef float v2f __attribute__((ext_vector_type(2)));

// decode 4 packed fp8(e4m3) -> 4 f32 via HW cvt
__device__ __forceinline__ float4 dec8(unsigned v) {
  v2f lo = __builtin_amdgcn_cvt_pk_f32_fp8(v, false);
  v2f hi = __builtin_amdgcn_cvt_pk_f32_fp8(v, true);
  return make_float4(lo.x, lo.y, hi.x, hi.y);
}

// bf16 in high 16 bits -> f32
__device__ __forceinline__ float bhi(unsigned u) { return __uint_as_float(u & 0xffff0000u); }

__device__ __forceinline__ void fma4(float4& a, float nn, float4 f) {
  a.x += nn * f.x; a.y += nn * f.y; a.z += nn * f.z; a.w += nn * f.w;
}

// ---- pass A1: per-chunk bucket histogram (LDS) + per-edge rank -------------
__global__ __launch_bounds__(1024) void kA_hist(const int* __restrict__ dst,
                                                int* __restrict__ counts,
                                                int* __restrict__ rawc,
                                                unsigned short* __restrict__ rank,
                                                int E, int chsz, int nbuk) {
  __shared__ unsigned lh[MAXBUK];
  const int b = blockIdx.x, t = threadIdx.x;
  for (int i = t; i < nbuk; i += 1024) lh[i] = 0u;
  __syncthreads();
  const int e0 = b * chsz, e1 = min(e0 + chsz, E);
  for (int e = e0 + t; e < e1; e += 1024) {
    int d = dst[e];
    rank[e] = (unsigned short)atomicAdd(&lh[d >> SHIFT], 1u);  // rank < 6250
  }
  __syncthreads();
  for (int i = t; i < nbuk; i += 1024) {
    counts[(size_t)i * NCH + b] = (int)lh[i];
    rawc[(size_t)i * NCH + b] = (int)lh[i];
  }
}

// ---- pass A2a: parallel exclusive scan, phase 1 (block-local + block sums) --
__global__ __launch_bounds__(1024) void kS1(int* __restrict__ counts,
                                            int* __restrict__ bsum, int M) {
  __shared__ int buf[1024];
  const int t = threadIdx.x;
  const int i = blockIdx.x * 1024 + t;
  int v = (i < M) ? counts[i] : 0;
  buf[t] = v;
  __syncthreads();
  for (int off = 1; off < 1024; off <<= 1) {
    int a = (t >= off) ? buf[t - off] : 0;
    __syncthreads();
    buf[t] += a;
    __syncthreads();
  }
  if (i < M) counts[i] = buf[t] - v;          // exclusive, block-local
  if (t == 1023) bsum[blockIdx.x] = buf[t];
}

// ---- pass A2b: add prefix of block sums (<=98 blocks, inline loop) ---------
__global__ __launch_bounds__(1024) void kS2(int* __restrict__ counts,
                                            const int* __restrict__ bsum, int M) {
  __shared__ int off;
  if (threadIdx.x == 0) {
    int s = 0;
    for (int b = 0; b < (int)blockIdx.x; ++b) s += bsum[b];
    off = s;
  }
  __syncthreads();
  int i = blockIdx.x * 1024 + threadIdx.x;
  if (i < M) counts[i] += off;
}

// ---- pass A3: LDS-staged scatter -> MONOTONE global writes -----------------
__global__ __launch_bounds__(1024) void kA_scat(const int* __restrict__ src,
                                                const int* __restrict__ dst,
                                                const float* __restrict__ w,
                                                const unsigned short* __restrict__ rank,
                                                const int* __restrict__ counts,
                                                const int* __restrict__ rawc,
                                                unsigned long long* __restrict__ rec,
                                                unsigned char* __restrict__ dl,
                                                int E, int chsz, int nbuk) {
  __shared__ unsigned long long srec[CHMAX];
  __shared__ unsigned spos[CHMAX];
  __shared__ int lh[MAXBUK];
  __shared__ int lpre[MAXBUK];
  __shared__ int gb[MAXBUK];
  const int b = blockIdx.x, t = threadIdx.x;
  if (t < MAXBUK) {
    int c = (t < nbuk) ? rawc[(size_t)t * NCH + b] : 0;
    lh[t] = c;
    lpre[t] = c;
    gb[t] = (t < nbuk) ? counts[(size_t)t * NCH + b] : 0;
  }
  __syncthreads();
  for (int off = 1; off < MAXBUK; off <<= 1) {
    int a = (t >= off && t < MAXBUK) ? lpre[t - off] : 0;
    __syncthreads();
    if (t < MAXBUK) lpre[t] += a;            // inclusive scan
    __syncthreads();
  }
  const int e0 = b * chsz, e1 = min(e0 + chsz, E);
  for (int e = e0 + t; e < e1; e += 1024) {
    int d = dst[e];
    int k = d >> SHIFT;
    int r = (int)rank[e];
    int lpos = lpre[k] - lh[k] + r;          // bucket-major local slot
    srec[lpos] = ((unsigned long long)(unsigned)__float_as_int(w[e]) << 32) |
                 (unsigned)src[e];
    spos[lpos] = (unsigned)(gb[k] + r) | ((unsigned)(d & (BWID - 1)) << 21);
  }
  __syncthreads();
  const int csz = e1 - e0;
  for (int i = t; i < csz; i += 1024) {
    unsigned u = spos[i];
    unsigned g = u & 0x1FFFFFu;              // gpos < E = 1.6M < 2^21
    rec[g] = srec[i];
    dl[g] = (unsigned char)(u >> 21);
  }
}

// ---- pass B: per-bucket counting sort -> PACKED sorted (u16 src|bf16 w) ----
__global__ __launch_bounds__(1024) void kB_sort(const unsigned long long* __restrict__ rec,
                                                const unsigned char* __restrict__ dl,
                                                const int* __restrict__ counts,
                                                unsigned* __restrict__ sorted,
                                                int* __restrict__ cnt,
                                                int* __restrict__ cursor,
                                                float* __restrict__ dinv,
                                                int E, int nbuk, int N) {
  __shared__ unsigned h[BWID];
  __shared__ unsigned pf[BWID];
  __shared__ unsigned cur[BWID];
  __shared__ float dg[BWID];
  const int B = blockIdx.x, t = threadIdx.x;
  const int bb = counts[(size_t)B * NCH];
  const int be = (B + 1 < nbuk) ? counts[(size_t)(B + 1) * NCH] : E;
  if (t < BWID) { h[t] = 0u; dg[t] = 0.0f; }
  __syncthreads();
  for (int i = bb + t; i < be; i += 1024) atomicAdd(&h[dl[i]], 1u);
  __syncthreads();
  if (t < BWID) pf[t] = h[t];
  __syncthreads();
  for (int off = 1; off < BWID; off <<= 1) {
    unsigned a = (t >= off && t < BWID) ? pf[t - off] : 0u;
    __syncthreads();
    if (t < BWID) pf[t] += a;
    __syncthreads();
  }
  if (t < BWID) cur[t] = pf[t] - h[t];       // exclusive prefix
  __syncthreads();
  for (int i = bb + t; i < be; i += 1024) {
    unsigned long long r = rec[i];
    int d = dl[i];
    unsigned pos = atomicAdd(&cur[d], 1u);
    float wv = __uint_as_float((unsigned)(r >> 32));
    unsigned wb = (unsigned)__bfloat16_as_ushort(__float2bfloat16(wv));
    sorted[(size_t)bb + pos] = (wb << 16) | ((unsigned)r & 0xFFFFu);  // src<65536
    atomicAdd(&dg[d], wv);                   // full-precision degree
  }
  __syncthreads();
  const int node = (B << SHIFT) + t;
  if (t < BWID && node < N) {
    cnt[node] = (int)h[t];
    cursor[node] = bb + (int)(pf[t] - h[t]);
    dinv[node] = rsqrtf(1.0f + dg[t]);       // +1 = self loop weight
  }
}

// ------- h = x @ W, output PACKED FP8 e4m3 (N x 16 words = 64 B/row) --------
__global__ __launch_bounds__(256) void k_gemm(const float* __restrict__ x,
                                              const float* __restrict__ W,
                                              unsigned* __restrict__ hb8, int N) {
  __shared__ float Ws[F * H];
  __shared__ float xs[NB * XS_STRIDE];
  const int t = threadIdx.x;
  {
    const float4* W4 = (const float4*)W;
    float4* Ws4 = (float4*)Ws;
#pragma unroll
    for (int i = 0; i < (F * H / 4) / 256; ++i) Ws4[t + i * 256] = W4[t + i * 256];
  }
  const int node0 = blockIdx.x * NB;
  {
    const float4* x4 = (const float4*)(x + (size_t)node0 * F);
    int lim = (N - node0 < NB ? N - node0 : NB) * (F / 4);
    for (int i = t; i < NB * (F / 4); i += 256) {
      int nl = i / (F / 4), kk = i % (F / 4);
      float4 v = (i < lim) ? x4[i] : make_float4(0.f, 0.f, 0.f, 0.f);
      *(float4*)&xs[nl * XS_STRIDE + kk * 4] = v;
    }
  }
  __syncthreads();
  const int f0 = (t & 15) * 4;
  const int nl0 = (t >> 4) * 2;
  float acc[2][4] = {};
  for (int k = 0; k < F; k += 4) {
    float xr[2][4];
    float wr[4][4];
    *(float4*)&xr[0][0] = *(const float4*)&xs[(nl0 + 0) * XS_STRIDE + k];
    *(float4*)&xr[1][0] = *(const float4*)&xs[(nl0 + 1) * XS_STRIDE + k];
#pragma unroll
    for (int i = 0; i < 4; ++i)
      *(float4*)&wr[i][0] = *(const float4*)&Ws[(k + i) * H + f0];
#pragma unroll
    for (int i = 0; i < 4; ++i)
#pragma unroll
      for (int n = 0; n < 2; ++n)
#pragma unroll
        for (int j = 0; j < 4; ++j)
          acc[n][j] += xr[n][i] * wr[i][j];
  }
#pragma unroll
  for (int n = 0; n < 2; ++n) {
    int node = node0 + nl0 + n;
    if (node < N) {
      int pk = __builtin_amdgcn_cvt_pk_fp8_f32(acc[n][0], acc[n][1], 0, false);
      pk = __builtin_amdgcn_cvt_pk_fp8_f32(acc[n][2], acc[n][3], pk, true);
      hb8[(size_t)node * 16 + (f0 >> 2)] = (unsigned)pk;
    }
  }
}

// ---- gather-aggregate: 4 lanes/node x 16B row loads (4x fewer VMEM instrs) -
// Each 4-lane group owns one node; lane gl loads uint4 = 16 fp8 features.
// One wave-VMEM-instruction services 16 edges (was 4 in the 16-lane layout).
__global__ __launch_bounds__(256) void k_agg(const unsigned* __restrict__ sorted,
                                             const int* __restrict__ cursor,
                                             const int* __restrict__ cnt,
                                             const float* __restrict__ dinv,
                                             const unsigned char* __restrict__ hb8,
                                             const float* __restrict__ b,
                                             const float* __restrict__ fcw,
                                             float* __restrict__ partials, int N) {
  const int wid = threadIdx.x >> 6;
  const int lane = threadIdx.x & 63;
  const int g = lane >> 2;          // 0..15: node group within wave
  const int gl = lane & 3;          // lane in group: 16 features each
  const int n = blockIdx.x * 64 + wid * 16 + g;
  float p = 0.0f;
  if (n < N) {
    float dn = dinv[n];
    float dn2 = dn * dn;
    uint4 rn = *(const uint4*)(hb8 + ((size_t)n << 6) + (gl << 4));
    float4 s0v = dec8(rn.x), s1v = dec8(rn.y), s2v = dec8(rn.z), s3v = dec8(rn.w);
    const float4* bb4 = (const float4*)(b + (gl << 4));
    float4 a0 = bb4[0], a1 = bb4[1], a2 = bb4[2], a3 = bb4[3];
    fma4(a0, dn2, s0v); fma4(a1, dn2, s1v); fma4(a2, dn2, s2v); fma4(a3, dn2, s3v);
    int e = cursor[n];
    int end = e + cnt[n];
    for (; e + 1 < end; e += 2) {
      unsigned s0 = sorted[e];               // broadcast within group
      unsigned s1 = sorted[e + 1];
      unsigned i0 = s0 & 0xFFFFu, i1 = s1 & 0xFFFFu;
      uint4 r0 = *(const uint4*)(hb8 + ((size_t)i0 << 6) + (gl << 4));
      uint4 r1 = *(const uint4*)(hb8 + ((size_t)i1 << 6) + (gl << 4));
      float n0 = dn * dinv[i0] * bhi(s0);    // dinv: broadcast load
      float n1 = dn * dinv[i1] * bhi(s1);
      fma4(a0, n0, dec8(r0.x)); fma4(a1, n0, dec8(r0.y));
      fma4(a2, n0, dec8(r0.z)); fma4(a3, n0, dec8(r0.w));
      fma4(a0, n1, dec8(r1.x)); fma4(a1, n1, dec8(r1.y));
      fma4(a2, n1, dec8(r1.z)); fma4(a3, n1, dec8(r1.w));
    }
    if (e < end) {
      unsigned s0 = sorted[e];
      unsigned i0 = s0 & 0xFFFFu;
      uint4 r0 = *(const uint4*)(hb8 + ((size_t)i0 << 6) + (gl << 4));
      float n0 = dn * dinv[i0] * bhi(s0);
      fma4(a0, n0, dec8(r0.x)); fma4(a1, n0, dec8(r0.y));
      fma4(a2, n0, dec8(r0.z)); fma4(a3, n0, dec8(r0.w));
    }
    const float4* fw4 = (const float4*)(fcw + (size_t)n * H + (gl << 4));
    float4 f0 = fw4[0], f1 = fw4[1], f2 = fw4[2], f3 = fw4[3];
    p = fmaxf(a0.x, 0.f) * f0.x + fmaxf(a0.y, 0.f) * f0.y +
        fmaxf(a0.z, 0.f) * f0.z + fmaxf(a0.w, 0.f) * f0.w +
        fmaxf(a1.x, 0.f) * f1.x + fmaxf(a1.y, 0.f) * f1.y +
        fmaxf(a1.z, 0.f) * f1.z + fmaxf(a1.w, 0.f) * f1.w +
        fmaxf(a2.x, 0.f) * f2.x + fmaxf(a2.y, 0.f) * f2.y +
        fmaxf(a2.z, 0.f) * f2.z + fmaxf(a2.w, 0.f) * f2.w +
        fmaxf(a3.x, 0.f) * f3.x + fmaxf(a3.y, 0.f) * f3.y +
        fmaxf(a3.z, 0.f) * f3.z + fmaxf(a3.w, 0.f) * f3.w;
  }
  p += __shfl_xor(p, 1);
  p += __shfl_xor(p, 2);                     // full sum within 4-lane group
  __shared__ float ls[64];
  if (gl == 0) ls[wid * 16 + g] = p;
  __syncthreads();
  if (threadIdx.x == 0) {
    float s = 0.f;
#pragma unroll
    for (int i = 0; i < 64; ++i) s += ls[i];
    partials[blockIdx.x] = s;
  }
}

// ---------------- final: sum partials, + fc_b, sigmoid ----------------------
__global__ __launch_bounds__(1024) void k_fred(const float* __restrict__ partials,
                                               int M,
                                               const float* __restrict__ fcb,
                                               float* __restrict__ out) {
  const int t = threadIdx.x;
  float s = 0.0f;
  for (int i = t; i < M; i += 1024) s += partials[i];
#pragma unroll
  for (int off = 32; off > 0; off >>= 1) s += __shfl_down(s, off);
  __shared__ float ls[16];
  if ((t & 63) == 0) ls[t >> 6] = s;
  __syncthreads();
  if (t == 0) {
    float tot = 0.0f;
#pragma unroll
    for (int i = 0; i < 16; ++i) tot += ls[i];
    float logit = tot + fcb[0];
    out[0] = 1.0f / (1.0f + expf(-logit));
  }
}

extern "C" void kernel_launch(void* const* d_in, const int* in_sizes, int n_in,
                              void* d_out, int out_size, void* d_ws, size_t ws_size,
                              hipStream_t stream) {
  const float* x      = (const float*)d_in[0];
  const int*   elist  = (const int*)d_in[1];
  const float* eattr  = (const float*)d_in[2];
  const float* conv_w = (const float*)d_in[3];
  const float* conv_b = (const float*)d_in[4];
  const float* fc_w   = (const float*)d_in[5];
  const float* fc_b   = (const float*)d_in[6];
  float* out = (float*)d_out;

  const int N = in_sizes[0] / F;   // 50000
  const int E = in_sizes[2];       // 1,600,000
  const int* src = elist;
  const int* dst = elist + E;

  const int chsz = (E + NCH - 1) / NCH;        // 6250 (<= CHMAX)
  const int nbuk = ((N - 1) >> SHIFT) + 1;     // 391
  const int M = nbuk * NCH;                    // 100096
  const int nS = (M + 1023) / 1024;            // 98

  char* wsb = (char*)d_ws;
  unsigned long long* rec = (unsigned long long*)wsb;          // E*8
  unsigned* sorted = (unsigned*)(rec + E);                     // E*4 (packed)
  unsigned* hb8 = sorted + E;                                  // N*64 B
  int*   counts = (int*)(hb8 + (size_t)N * 16);                // M*4
  int*   rawc   = counts + M;                                  // M*4
  int*   cnt    = rawc + M;                                    // N*4
  int*   cursor = cnt + N;                                     // N*4
  float* dinv   = (float*)(cursor + N);                        // N*4
  const int nAgg = (N + 63) / 64;                              // 782
  float* partials = dinv + N;                                  // nAgg*4
  int*   bsum   = (int*)(partials + nAgg);                     // nS*4
  unsigned short* rank = (unsigned short*)(bsum + nS);         // E*2
  unsigned char* dl = (unsigned char*)(rank + E);              // E*1

  kA_hist<<<NCH, 1024, 0, stream>>>(dst, counts, rawc, rank, E, chsz, nbuk);
  kS1<<<nS, 1024, 0, stream>>>(counts, bsum, M);
  kS2<<<nS, 1024, 0, stream>>>(counts, bsum, M);
  kA_scat<<<NCH, 1024, 0, stream>>>(src, dst, eattr, rank, counts, rawc, rec,
                                    dl, E, chsz, nbuk);
  kB_sort<<<nbuk, 1024, 0, stream>>>(rec, dl, counts, sorted, cnt, cursor, dinv,
                                     E, nbuk, N);
  k_gemm<<<(N + NB - 1) / NB, 256, 0, stream>>>(x, conv_w, hb8, N);
  k_agg<<<nAgg, 256, 0, stream>>>(sorted, cursor, cnt, dinv,
                                  (const unsigned char*)hb8, conv_b, fc_w,
                                  partials, N);
  k_fred<<<1, 1024, 0, stream>>>(partials, nAgg, fc_b, out);
}

// Round 15
// 177.376 us; speedup vs baseline: 1.0522x; 1.0522x over previous
//
#include <hip/hip_runtime.h>
#include <hip/hip_bf16.h>
#include <math.h>

constexpr int F = 128;        // in features
constexpr int H = 64;         // out features
constexpr int NB = 32;        // nodes per gemm block
constexpr int XS_STRIDE = F + 4;
constexpr int NCH = 256;      // edge chunks (pass-A blocks) == #CUs
constexpr int SHIFT = 7;      // log2(nodes per bucket)
constexpr int BWID = 1 << SHIFT;   // 128 nodes per bucket
constexpr int MAXBUK = 512;   // >= nbuk = ceil(N/128) = 391
constexpr int CHMAX = 6400;   // >= chsz = ceil(E/NCH) = 6250

typedef float v2f __attribute__((ext_vector_type(2)));

// decode 4 packed fp8(e4m3) -> 4 f32 via HW cvt
__device__ __forceinline__ float4 dec8(unsigned v) {
  v2f lo = __builtin_amdgcn_cvt_pk_f32_fp8(v, false);
  v2f hi = __builtin_amdgcn_cvt_pk_f32_fp8(v, true);
  return make_float4(lo.x, lo.y, hi.x, hi.y);
}

// bf16 in high 16 bits -> f32
__device__ __forceinline__ float bhi(unsigned u) { return __uint_as_float(u & 0xffff0000u); }

// ---- pass A1: per-chunk bucket histogram (LDS) + per-edge rank -------------
__global__ __launch_bounds__(1024) void kA_hist(const int* __restrict__ dst,
                                                int* __restrict__ counts,
                                                int* __restrict__ rawc,
                                                unsigned short* __restrict__ rank,
                                                int E, int chsz, int nbuk) {
  __shared__ unsigned lh[MAXBUK];
  const int b = blockIdx.x, t = threadIdx.x;
  for (int i = t; i < nbuk; i += 1024) lh[i] = 0u;
  __syncthreads();
  const int e0 = b * chsz, e1 = min(e0 + chsz, E);
  for (int e = e0 + t; e < e1; e += 1024) {
    int d = dst[e];
    rank[e] = (unsigned short)atomicAdd(&lh[d >> SHIFT], 1u);  // rank < 6250
  }
  __syncthreads();
  for (int i = t; i < nbuk; i += 1024) {
    counts[(size_t)i * NCH + b] = (int)lh[i];
    rawc[(size_t)i * NCH + b] = (int)lh[i];
  }
}

// ---- pass A2a: parallel exclusive scan, phase 1 (block-local + block sums) --
__global__ __launch_bounds__(1024) void kS1(int* __restrict__ counts,
                                            int* __restrict__ bsum, int M) {
  __shared__ int buf[1024];
  const int t = threadIdx.x;
  const int i = blockIdx.x * 1024 + t;
  int v = (i < M) ? counts[i] : 0;
  buf[t] = v;
  __syncthreads();
  for (int off = 1; off < 1024; off <<= 1) {
    int a = (t >= off) ? buf[t - off] : 0;
    __syncthreads();
    buf[t] += a;
    __syncthreads();
  }
  if (i < M) counts[i] = buf[t] - v;          // exclusive, block-local
  if (t == 1023) bsum[blockIdx.x] = buf[t];
}

// ---- pass A2b: add prefix of block sums (<=98 blocks, inline loop) ---------
__global__ __launch_bounds__(1024) void kS2(int* __restrict__ counts,
                                            const int* __restrict__ bsum, int M) {
  __shared__ int off;
  if (threadIdx.x == 0) {
    int s = 0;
    for (int b = 0; b < (int)blockIdx.x; ++b) s += bsum[b];
    off = s;
  }
  __syncthreads();
  int i = blockIdx.x * 1024 + threadIdx.x;
  if (i < M) counts[i] += off;
}

// ---- pass A3: LDS-staged scatter -> MONOTONE global writes -----------------
__global__ __launch_bounds__(1024) void kA_scat(const int* __restrict__ src,
                                                const int* __restrict__ dst,
                                                const float* __restrict__ w,
                                                const unsigned short* __restrict__ rank,
                                                const int* __restrict__ counts,
                                                const int* __restrict__ rawc,
                                                unsigned long long* __restrict__ rec,
                                                unsigned char* __restrict__ dl,
                                                int E, int chsz, int nbuk) {
  __shared__ unsigned long long srec[CHMAX];
  __shared__ unsigned spos[CHMAX];
  __shared__ int lh[MAXBUK];
  __shared__ int lpre[MAXBUK];
  __shared__ int gb[MAXBUK];
  const int b = blockIdx.x, t = threadIdx.x;
  if (t < MAXBUK) {
    int c = (t < nbuk) ? rawc[(size_t)t * NCH + b] : 0;
    lh[t] = c;
    lpre[t] = c;
    gb[t] = (t < nbuk) ? counts[(size_t)t * NCH + b] : 0;
  }
  __syncthreads();
  for (int off = 1; off < MAXBUK; off <<= 1) {
    int a = (t >= off && t < MAXBUK) ? lpre[t - off] : 0;
    __syncthreads();
    if (t < MAXBUK) lpre[t] += a;            // inclusive scan
    __syncthreads();
  }
  const int e0 = b * chsz, e1 = min(e0 + chsz, E);
  for (int e = e0 + t; e < e1; e += 1024) {
    int d = dst[e];
    int k = d >> SHIFT;
    int r = (int)rank[e];
    int lpos = lpre[k] - lh[k] + r;          // bucket-major local slot
    srec[lpos] = ((unsigned long long)(unsigned)__float_as_int(w[e]) << 32) |
                 (unsigned)src[e];
    spos[lpos] = (unsigned)(gb[k] + r) | ((unsigned)(d & (BWID - 1)) << 21);
  }
  __syncthreads();
  const int csz = e1 - e0;
  for (int i = t; i < csz; i += 1024) {
    unsigned u = spos[i];
    unsigned g = u & 0x1FFFFFu;              // gpos < E = 1.6M < 2^21
    rec[g] = srec[i];
    dl[g] = (unsigned char)(u >> 21);
  }
}

// ---- pass B: per-bucket counting sort -> PACKED sorted (u16 src|bf16 w) ----
__global__ __launch_bounds__(1024) void kB_sort(const unsigned long long* __restrict__ rec,
                                                const unsigned char* __restrict__ dl,
                                                const int* __restrict__ counts,
                                                unsigned* __restrict__ sorted,
                                                int* __restrict__ cnt,
                                                int* __restrict__ cursor,
                                                float* __restrict__ dinv,
                                                int E, int nbuk, int N) {
  __shared__ unsigned h[BWID];
  __shared__ unsigned pf[BWID];
  __shared__ unsigned cur[BWID];
  __shared__ float dg[BWID];
  const int B = blockIdx.x, t = threadIdx.x;
  const int bb = counts[(size_t)B * NCH];
  const int be = (B + 1 < nbuk) ? counts[(size_t)(B + 1) * NCH] : E;
  if (t < BWID) { h[t] = 0u; dg[t] = 0.0f; }
  __syncthreads();
  for (int i = bb + t; i < be; i += 1024) atomicAdd(&h[dl[i]], 1u);
  __syncthreads();
  if (t < BWID) pf[t] = h[t];
  __syncthreads();
  for (int off = 1; off < BWID; off <<= 1) {
    unsigned a = (t >= off && t < BWID) ? pf[t - off] : 0u;
    __syncthreads();
    if (t < BWID) pf[t] += a;
    __syncthreads();
  }
  if (t < BWID) cur[t] = pf[t] - h[t];       // exclusive prefix
  __syncthreads();
  for (int i = bb + t; i < be; i += 1024) {
    unsigned long long r = rec[i];
    int d = dl[i];
    unsigned pos = atomicAdd(&cur[d], 1u);
    float wv = __uint_as_float((unsigned)(r >> 32));
    unsigned wb = (unsigned)__bfloat16_as_ushort(__float2bfloat16(wv));
    sorted[(size_t)bb + pos] = (wb << 16) | ((unsigned)r & 0xFFFFu);  // src<65536
    atomicAdd(&dg[d], wv);                   // full-precision degree
  }
  __syncthreads();
  const int node = (B << SHIFT) + t;
  if (t < BWID && node < N) {
    cnt[node] = (int)h[t];
    cursor[node] = bb + (int)(pf[t] - h[t]);
    dinv[node] = rsqrtf(1.0f + dg[t]);       // +1 = self loop weight
  }
}

// ------- h = x @ W, output PACKED FP8 e4m3 (N x 16 words = 64 B/row) --------
__global__ __launch_bounds__(256) void k_gemm(const float* __restrict__ x,
                                              const float* __restrict__ W,
                                              unsigned* __restrict__ hb8, int N) {
  __shared__ float Ws[F * H];
  __shared__ float xs[NB * XS_STRIDE];
  const int t = threadIdx.x;
  {
    const float4* W4 = (const float4*)W;
    float4* Ws4 = (float4*)Ws;
#pragma unroll
    for (int i = 0; i < (F * H / 4) / 256; ++i) Ws4[t + i * 256] = W4[t + i * 256];
  }
  const int node0 = blockIdx.x * NB;
  {
    const float4* x4 = (const float4*)(x + (size_t)node0 * F);
    int lim = (N - node0 < NB ? N - node0 : NB) * (F / 4);
    for (int i = t; i < NB * (F / 4); i += 256) {
      int nl = i / (F / 4), kk = i % (F / 4);
      float4 v = (i < lim) ? x4[i] : make_float4(0.f, 0.f, 0.f, 0.f);
      *(float4*)&xs[nl * XS_STRIDE + kk * 4] = v;
    }
  }
  __syncthreads();
  const int f0 = (t & 15) * 4;
  const int nl0 = (t >> 4) * 2;
  float acc[2][4] = {};
  for (int k = 0; k < F; k += 4) {
    float xr[2][4];
    float wr[4][4];
    *(float4*)&xr[0][0] = *(const float4*)&xs[(nl0 + 0) * XS_STRIDE + k];
    *(float4*)&xr[1][0] = *(const float4*)&xs[(nl0 + 1) * XS_STRIDE + k];
#pragma unroll
    for (int i = 0; i < 4; ++i)
      *(float4*)&wr[i][0] = *(const float4*)&Ws[(k + i) * H + f0];
#pragma unroll
    for (int i = 0; i < 4; ++i)
#pragma unroll
      for (int n = 0; n < 2; ++n)
#pragma unroll
        for (int j = 0; j < 4; ++j)
          acc[n][j] += xr[n][i] * wr[i][j];
  }
#pragma unroll
  for (int n = 0; n < 2; ++n) {
    int node = node0 + nl0 + n;
    if (node < N) {
      int pk = __builtin_amdgcn_cvt_pk_fp8_f32(acc[n][0], acc[n][1], 0, false);
      pk = __builtin_amdgcn_cvt_pk_fp8_f32(acc[n][2], acc[n][3], pk, true);
      hb8[(size_t)node * 16 + (f0 >> 2)] = (unsigned)pk;
    }
  }
}

// ---- gather-aggregate (fp8 h, packed 4B edges): 8-deep MLP, 16-lane layout -
__global__ __launch_bounds__(256) void k_agg(const unsigned* __restrict__ sorted,
                                             const int* __restrict__ cursor,
                                             const int* __restrict__ cnt,
                                             const float* __restrict__ dinv,
                                             const unsigned char* __restrict__ hb8,
                                             const float* __restrict__ b,
                                             const float* __restrict__ fcw,
                                             float* __restrict__ partials, int N) {
  const int wid = threadIdx.x >> 6;
  const int lane = threadIdx.x & 63;
  const int seg = lane >> 4;        // 0..3: node segment within wave
  const int sl = lane & 15;         // lane within segment: 16 x 4 feats
  const int n = blockIdx.x * 16 + wid * 4 + seg;
  float p = 0.0f;
  if (n < N) {
    float dn = dinv[n];
    unsigned rn = *(const unsigned*)(hb8 + ((size_t)n << 6) + (sl << 2));
    float4 sv = dec8(rn);
    float4 bb = ((const float4*)b)[sl];
    float dn2 = dn * dn;
    float ax = bb.x + dn2 * sv.x;
    float ay = bb.y + dn2 * sv.y;
    float az = bb.z + dn2 * sv.z;
    float aw = bb.w + dn2 * sv.w;
    int e = cursor[n];
    int end = e + cnt[n];
    // 8 independent gather chains in flight per iteration
    for (; e + 7 < end; e += 8) {
      unsigned s0 = sorted[e + 0], s1 = sorted[e + 1];
      unsigned s2 = sorted[e + 2], s3 = sorted[e + 3];
      unsigned s4 = sorted[e + 4], s5 = sorted[e + 5];
      unsigned s6 = sorted[e + 6], s7 = sorted[e + 7];
      unsigned i0 = s0 & 0xFFFFu, i1 = s1 & 0xFFFFu, i2 = s2 & 0xFFFFu,
               i3 = s3 & 0xFFFFu, i4 = s4 & 0xFFFFu, i5 = s5 & 0xFFFFu,
               i6 = s6 & 0xFFFFu, i7 = s7 & 0xFFFFu;
      unsigned r0 = *(const unsigned*)(hb8 + ((size_t)i0 << 6) + (sl << 2));
      unsigned r1 = *(const unsigned*)(hb8 + ((size_t)i1 << 6) + (sl << 2));
      unsigned r2 = *(const unsigned*)(hb8 + ((size_t)i2 << 6) + (sl << 2));
      unsigned r3 = *(const unsigned*)(hb8 + ((size_t)i3 << 6) + (sl << 2));
      unsigned r4 = *(const unsigned*)(hb8 + ((size_t)i4 << 6) + (sl << 2));
      unsigned r5 = *(const unsigned*)(hb8 + ((size_t)i5 << 6) + (sl << 2));
      unsigned r6 = *(const unsigned*)(hb8 + ((size_t)i6 << 6) + (sl << 2));
      unsigned r7 = *(const unsigned*)(hb8 + ((size_t)i7 << 6) + (sl << 2));
      float n0 = dn * dinv[i0] * bhi(s0);
      float n1 = dn * dinv[i1] * bhi(s1);
      float n2 = dn * dinv[i2] * bhi(s2);
      float n3 = dn * dinv[i3] * bhi(s3);
      float n4 = dn * dinv[i4] * bhi(s4);
      float n5 = dn * dinv[i5] * bhi(s5);
      float n6 = dn * dinv[i6] * bhi(s6);
      float n7 = dn * dinv[i7] * bhi(s7);
      float4 f0 = dec8(r0), f1 = dec8(r1), f2 = dec8(r2), f3 = dec8(r3);
      float4 f4 = dec8(r4), f5 = dec8(r5), f6 = dec8(r6), f7 = dec8(r7);
      ax += n0 * f0.x + n1 * f1.x + n2 * f2.x + n3 * f3.x +
            n4 * f4.x + n5 * f5.x + n6 * f6.x + n7 * f7.x;
      ay += n0 * f0.y + n1 * f1.y + n2 * f2.y + n3 * f3.y +
            n4 * f4.y + n5 * f5.y + n6 * f6.y + n7 * f7.y;
      az += n0 * f0.z + n1 * f1.z + n2 * f2.z + n3 * f3.z +
            n4 * f4.z + n5 * f5.z + n6 * f6.z + n7 * f7.z;
      aw += n0 * f0.w + n1 * f1.w + n2 * f2.w + n3 * f3.w +
            n4 * f4.w + n5 * f5.w + n6 * f6.w + n7 * f7.w;
    }
    for (; e < end; ++e) {
      unsigned s0 = sorted[e];
      unsigned i0 = s0 & 0xFFFFu;
      unsigned r0 = *(const unsigned*)(hb8 + ((size_t)i0 << 6) + (sl << 2));
      float n0 = dn * dinv[i0] * bhi(s0);
      float4 f0 = dec8(r0);
      ax += n0 * f0.x;
      ay += n0 * f0.y;
      az += n0 * f0.z;
      aw += n0 * f0.w;
    }
    float4 fw = ((const float4*)fcw)[(size_t)n * 16 + sl];
    p = fmaxf(ax, 0.f) * fw.x + fmaxf(ay, 0.f) * fw.y +
        fmaxf(az, 0.f) * fw.z + fmaxf(aw, 0.f) * fw.w;
  }
  p += __shfl_down(p, 8);
  p += __shfl_down(p, 4);
  p += __shfl_down(p, 2);
  p += __shfl_down(p, 1);
  __shared__ float ls[16];
  if (sl == 0) ls[wid * 4 + seg] = p;
  __syncthreads();
  if (threadIdx.x == 0) {
    float s = 0.f;
#pragma unroll
    for (int i = 0; i < 16; ++i) s += ls[i];
    partials[blockIdx.x] = s;
  }
}

// ---------------- final: sum partials, + fc_b, sigmoid ----------------------
__global__ __launch_bounds__(1024) void k_fred(const float* __restrict__ partials,
                                               int M,
                                               const float* __restrict__ fcb,
                                               float* __restrict__ out) {
  const int t = threadIdx.x;
  float s = 0.0f;
  for (int i = t; i < M; i += 1024) s += partials[i];
#pragma unroll
  for (int off = 32; off > 0; off >>= 1) s += __shfl_down(s, off);
  __shared__ float ls[16];
  if ((t & 63) == 0) ls[t >> 6] = s;
  __syncthreads();
  if (t == 0) {
    float tot = 0.0f;
#pragma unroll
    for (int i = 0; i < 16; ++i) tot += ls[i];
    float logit = tot + fcb[0];
    out[0] = 1.0f / (1.0f + expf(-logit));
  }
}

extern "C" void kernel_launch(void* const* d_in, const int* in_sizes, int n_in,
                              void* d_out, int out_size, void* d_ws, size_t ws_size,
                              hipStream_t stream) {
  const float* x      = (const float*)d_in[0];
  const int*   elist  = (const int*)d_in[1];
  const float* eattr  = (const float*)d_in[2];
  const float* conv_w = (const float*)d_in[3];
  const float* conv_b = (const float*)d_in[4];
  const float* fc_w   = (const float*)d_in[5];
  const float* fc_b   = (const float*)d_in[6];
  float* out = (float*)d_out;

  const int N = in_sizes[0] / F;   // 50000
  const int E = in_sizes[2];       // 1,600,000
  const int* src = elist;
  const int* dst = elist + E;

  const int chsz = (E + NCH - 1) / NCH;        // 6250 (<= CHMAX)
  const int nbuk = ((N - 1) >> SHIFT) + 1;     // 391
  const int M = nbuk * NCH;                    // 100096
  const int nS = (M + 1023) / 1024;            // 98

  char* wsb = (char*)d_ws;
  unsigned long long* rec = (unsigned long long*)wsb;          // E*8
  unsigned* sorted = (unsigned*)(rec + E);                     // E*4 (packed)
  unsigned* hb8 = sorted + E;                                  // N*64 B
  int*   counts = (int*)(hb8 + (size_t)N * 16);                // M*4
  int*   rawc   = counts + M;                                  // M*4
  int*   cnt    = rawc + M;                                    // N*4
  int*   cursor = cnt + N;                                     // N*4
  float* dinv   = (float*)(cursor + N);                        // N*4
  const int nAgg = (N + 15) / 16;
  float* partials = dinv + N;                                  // nAgg*4
  int*   bsum   = (int*)(partials + nAgg);                     // nS*4
  unsigned short* rank = (unsigned short*)(bsum + nS);         // E*2
  unsigned char* dl = (unsigned char*)(rank + E);              // E*1

  kA_hist<<<NCH, 1024, 0, stream>>>(dst, counts, rawc, rank, E, chsz, nbuk);
  kS1<<<nS, 1024, 0, stream>>>(counts, bsum, M);
  kS2<<<nS, 1024, 0, stream>>>(counts, bsum, M);
  kA_scat<<<NCH, 1024, 0, stream>>>(src, dst, eattr, rank, counts, rawc, rec,
                                    dl, E, chsz, nbuk);
  kB_sort<<<nbuk, 1024, 0, stream>>>(rec, dl, counts, sorted, cnt, cursor, dinv,
                                     E, nbuk, N);
  k_gemm<<<(N + NB - 1) / NB, 256, 0, stream>>>(x, conv_w, hb8, N);
  k_agg<<<nAgg, 256, 0, stream>>>(sorted, cursor, cnt, dinv,
                                  (const unsigned char*)hb8, conv_b, fc_w,
                                  partials, N);
  k_fred<<<1, 1024, 0, stream>>>(partials, nAgg, fc_b, out);
}

// Round 16
// 177.289 us; speedup vs baseline: 1.0527x; 1.0005x over previous
//
#include <hip/hip_runtime.h>
#include <hip/hip_bf16.h>
#include <math.h>

constexpr int F = 128;        // in features
constexpr int H = 64;         // out features
constexpr int NB = 32;        // nodes per gemm block
constexpr int XS_STRIDE = F + 4;
constexpr int NCH = 256;      // edge chunks (pass-A blocks) == #CUs
constexpr int SHIFT = 7;      // log2(nodes per bucket)
constexpr int BWID = 1 << SHIFT;   // 128 nodes per bucket
constexpr int MAXBUK = 512;   // >= nbuk = ceil(N/128) = 391
constexpr int CHMAX = 6400;   // >= chsz = ceil(E/NCH) = 6250
constexpr int BCAP = 5632;    // kB_sort LDS staging cap (mean 4092, sigma~64)

typedef float v2f __attribute__((ext_vector_type(2)));

// decode 4 packed fp8(e4m3) -> 4 f32 via HW cvt
__device__ __forceinline__ float4 dec8(unsigned v) {
  v2f lo = __builtin_amdgcn_cvt_pk_f32_fp8(v, false);
  v2f hi = __builtin_amdgcn_cvt_pk_f32_fp8(v, true);
  return make_float4(lo.x, lo.y, hi.x, hi.y);
}

// bf16 in high 16 bits -> f32
__device__ __forceinline__ float bhi(unsigned u) { return __uint_as_float(u & 0xffff0000u); }

// ---- pass A1: per-chunk bucket histogram (LDS) + per-edge rank -------------
__global__ __launch_bounds__(1024) void kA_hist(const int* __restrict__ dst,
                                                int* __restrict__ counts,
                                                int* __restrict__ rawc,
                                                unsigned short* __restrict__ rank,
                                                int E, int chsz, int nbuk) {
  __shared__ unsigned lh[MAXBUK];
  const int b = blockIdx.x, t = threadIdx.x;
  for (int i = t; i < nbuk; i += 1024) lh[i] = 0u;
  __syncthreads();
  const int e0 = b * chsz, e1 = min(e0 + chsz, E);
  for (int e = e0 + t; e < e1; e += 1024) {
    int d = dst[e];
    rank[e] = (unsigned short)atomicAdd(&lh[d >> SHIFT], 1u);  // rank < 6250
  }
  __syncthreads();
  for (int i = t; i < nbuk; i += 1024) {
    counts[(size_t)i * NCH + b] = (int)lh[i];
    rawc[(size_t)i * NCH + b] = (int)lh[i];
  }
}

// ---- pass A2a: parallel exclusive scan, phase 1 (block-local + block sums) --
__global__ __launch_bounds__(1024) void kS1(int* __restrict__ counts,
                                            int* __restrict__ bsum, int M) {
  __shared__ int buf[1024];
  const int t = threadIdx.x;
  const int i = blockIdx.x * 1024 + t;
  int v = (i < M) ? counts[i] : 0;
  buf[t] = v;
  __syncthreads();
  for (int off = 1; off < 1024; off <<= 1) {
    int a = (t >= off) ? buf[t - off] : 0;
    __syncthreads();
    buf[t] += a;
    __syncthreads();
  }
  if (i < M) counts[i] = buf[t] - v;          // exclusive, block-local
  if (t == 1023) bsum[blockIdx.x] = buf[t];
}

// ---- pass A2b: add prefix of block sums (<=98 blocks, inline loop) ---------
__global__ __launch_bounds__(1024) void kS2(int* __restrict__ counts,
                                            const int* __restrict__ bsum, int M) {
  __shared__ int off;
  if (threadIdx.x == 0) {
    int s = 0;
    for (int b = 0; b < (int)blockIdx.x; ++b) s += bsum[b];
    off = s;
  }
  __syncthreads();
  int i = blockIdx.x * 1024 + threadIdx.x;
  if (i < M) counts[i] += off;
}

// ---- pass A3: LDS-staged scatter -> MONOTONE writes of FINAL 4B records ----
__global__ __launch_bounds__(1024) void kA_scat(const int* __restrict__ src,
                                                const int* __restrict__ dst,
                                                const float* __restrict__ w,
                                                const unsigned short* __restrict__ rank,
                                                const int* __restrict__ counts,
                                                const int* __restrict__ rawc,
                                                unsigned* __restrict__ rec4,
                                                unsigned char* __restrict__ dl,
                                                int E, int chsz, int nbuk) {
  __shared__ unsigned srec[CHMAX];
  __shared__ unsigned spos[CHMAX];
  __shared__ int lh[MAXBUK];
  __shared__ int lpre[MAXBUK];
  __shared__ int gb[MAXBUK];
  const int b = blockIdx.x, t = threadIdx.x;
  if (t < MAXBUK) {
    int c = (t < nbuk) ? rawc[(size_t)t * NCH + b] : 0;
    lh[t] = c;
    lpre[t] = c;
    gb[t] = (t < nbuk) ? counts[(size_t)t * NCH + b] : 0;
  }
  __syncthreads();
  for (int off = 1; off < MAXBUK; off <<= 1) {
    int a = (t >= off && t < MAXBUK) ? lpre[t - off] : 0;
    __syncthreads();
    if (t < MAXBUK) lpre[t] += a;            // inclusive scan
    __syncthreads();
  }
  const int e0 = b * chsz, e1 = min(e0 + chsz, E);
  for (int e = e0 + t; e < e1; e += 1024) {
    int d = dst[e];
    int k = d >> SHIFT;
    int r = (int)rank[e];
    int lpos = lpre[k] - lh[k] + r;          // bucket-major local slot
    unsigned wb = (unsigned)__bfloat16_as_ushort(__float2bfloat16(w[e]));
    srec[lpos] = (wb << 16) | (unsigned)src[e];   // final packed format
    spos[lpos] = (unsigned)(gb[k] + r) | ((unsigned)(d & (BWID - 1)) << 21);
  }
  __syncthreads();
  const int csz = e1 - e0;
  for (int i = t; i < csz; i += 1024) {
    unsigned u = spos[i];
    unsigned g = u & 0x1FFFFFu;              // gpos < E = 1.6M < 2^21
    rec4[g] = srec[i];
    dl[g] = (unsigned char)(u >> 21);
  }
}

// ---- pass B: per-bucket counting sort, SINGLE global read via LDS staging --
__global__ __launch_bounds__(1024) void kB_sort(const unsigned* __restrict__ rec4,
                                                const unsigned char* __restrict__ dl,
                                                const int* __restrict__ counts,
                                                unsigned* __restrict__ sorted,
                                                int* __restrict__ cnt,
                                                int* __restrict__ cursor,
                                                float* __restrict__ dinv,
                                                int E, int nbuk, int N) {
  __shared__ unsigned sr[BCAP];
  __shared__ unsigned char sd[BCAP];
  __shared__ unsigned h[BWID];
  __shared__ unsigned pf[BWID];
  __shared__ unsigned cur[BWID];
  __shared__ float dg[BWID];
  const int B = blockIdx.x, t = threadIdx.x;
  const int bb = counts[(size_t)B * NCH];
  const int be = (B + 1 < nbuk) ? counts[(size_t)(B + 1) * NCH] : E;
  const int sz = be - bb;
  const bool fit = (sz <= BCAP);
  if (t < BWID) { h[t] = 0u; dg[t] = 0.0f; }
  __syncthreads();
  if (fit) {
    for (int i = t; i < sz; i += 1024) { sr[i] = rec4[bb + i]; sd[i] = dl[bb + i]; }
    __syncthreads();
    for (int i = t; i < sz; i += 1024) atomicAdd(&h[sd[i]], 1u);
  } else {
    for (int i = bb + t; i < be; i += 1024) atomicAdd(&h[dl[i]], 1u);
  }
  __syncthreads();
  if (t < BWID) pf[t] = h[t];
  __syncthreads();
  for (int off = 1; off < BWID; off <<= 1) {
    unsigned a = (t >= off && t < BWID) ? pf[t - off] : 0u;
    __syncthreads();
    if (t < BWID) pf[t] += a;
    __syncthreads();
  }
  if (t < BWID) cur[t] = pf[t] - h[t];       // exclusive prefix
  __syncthreads();
  if (fit) {
    for (int i = t; i < sz; i += 1024) {
      unsigned r = sr[i];
      int d = sd[i];
      unsigned pos = atomicAdd(&cur[d], 1u);
      sorted[(size_t)bb + pos] = r;          // ~16 KB window, one XCD: merges
      atomicAdd(&dg[d], bhi(r));             // bf16 w, f32 accumulate
    }
  } else {
    for (int i = bb + t; i < be; i += 1024) {
      unsigned r = rec4[i];
      int d = dl[i];
      unsigned pos = atomicAdd(&cur[d], 1u);
      sorted[(size_t)bb + pos] = r;
      atomicAdd(&dg[d], bhi(r));
    }
  }
  __syncthreads();
  const int node = (B << SHIFT) + t;
  if (t < BWID && node < N) {
    cnt[node] = (int)h[t];
    cursor[node] = bb + (int)(pf[t] - h[t]);
    dinv[node] = rsqrtf(1.0f + dg[t]);       // +1 = self loop weight
  }
}

// ------- h = x @ W, output PACKED FP8 e4m3 (N x 16 words = 64 B/row) --------
__global__ __launch_bounds__(256) void k_gemm(const float* __restrict__ x,
                                              const float* __restrict__ W,
                                              unsigned* __restrict__ hb8, int N) {
  __shared__ float Ws[F * H];
  __shared__ float xs[NB * XS_STRIDE];
  const int t = threadIdx.x;
  {
    const float4* W4 = (const float4*)W;
    float4* Ws4 = (float4*)Ws;
#pragma unroll
    for (int i = 0; i < (F * H / 4) / 256; ++i) Ws4[t + i * 256] = W4[t + i * 256];
  }
  const int node0 = blockIdx.x * NB;
  {
    const float4* x4 = (const float4*)(x + (size_t)node0 * F);
    int lim = (N - node0 < NB ? N - node0 : NB) * (F / 4);
    for (int i = t; i < NB * (F / 4); i += 256) {
      int nl = i / (F / 4), kk = i % (F / 4);
      float4 v = (i < lim) ? x4[i] : make_float4(0.f, 0.f, 0.f, 0.f);
      *(float4*)&xs[nl * XS_STRIDE + kk * 4] = v;
    }
  }
  __syncthreads();
  const int f0 = (t & 15) * 4;
  const int nl0 = (t >> 4) * 2;
  float acc[2][4] = {};
  for (int k = 0; k < F; k += 4) {
    float xr[2][4];
    float wr[4][4];
    *(float4*)&xr[0][0] = *(const float4*)&xs[(nl0 + 0) * XS_STRIDE + k];
    *(float4*)&xr[1][0] = *(const float4*)&xs[(nl0 + 1) * XS_STRIDE + k];
#pragma unroll
    for (int i = 0; i < 4; ++i)
      *(float4*)&wr[i][0] = *(const float4*)&Ws[(k + i) * H + f0];
#pragma unroll
    for (int i = 0; i < 4; ++i)
#pragma unroll
      for (int n = 0; n < 2; ++n)
#pragma unroll
        for (int j = 0; j < 4; ++j)
          acc[n][j] += xr[n][i] * wr[i][j];
  }
#pragma unroll
  for (int n = 0; n < 2; ++n) {
    int node = node0 + nl0 + n;
    if (node < N) {
      int pk = __builtin_amdgcn_cvt_pk_fp8_f32(acc[n][0], acc[n][1], 0, false);
      pk = __builtin_amdgcn_cvt_pk_fp8_f32(acc[n][2], acc[n][3], pk, true);
      hb8[(size_t)node * 16 + (f0 >> 2)] = (unsigned)pk;
    }
  }
}

// ---- gather-aggregate (fp8 h, packed 4B edges): 8-deep MLP, 16-lane layout -
__global__ __launch_bounds__(256) void k_agg(const unsigned* __restrict__ sorted,
                                             const int* __restrict__ cursor,
                                             const int* __restrict__ cnt,
                                             const float* __restrict__ dinv,
                                             const unsigned char* __restrict__ hb8,
                                             const float* __restrict__ b,
                                             const float* __restrict__ fcw,
                                             float* __restrict__ partials, int N) {
  const int wid = threadIdx.x >> 6;
  const int lane = threadIdx.x & 63;
  const int seg = lane >> 4;        // 0..3: node segment within wave
  const int sl = lane & 15;         // lane within segment: 16 x 4 feats
  const int n = blockIdx.x * 16 + wid * 4 + seg;
  float p = 0.0f;
  if (n < N) {
    float dn = dinv[n];
    unsigned rn = *(const unsigned*)(hb8 + ((size_t)n << 6) + (sl << 2));
    float4 sv = dec8(rn);
    float4 bb = ((const float4*)b)[sl];
    float dn2 = dn * dn;
    float ax = bb.x + dn2 * sv.x;
    float ay = bb.y + dn2 * sv.y;
    float az = bb.z + dn2 * sv.z;
    float aw = bb.w + dn2 * sv.w;
    int e = cursor[n];
    int end = e + cnt[n];
    // 8 independent gather chains in flight per iteration
    for (; e + 7 < end; e += 8) {
      unsigned s0 = sorted[e + 0], s1 = sorted[e + 1];
      unsigned s2 = sorted[e + 2], s3 = sorted[e + 3];
      unsigned s4 = sorted[e + 4], s5 = sorted[e + 5];
      unsigned s6 = sorted[e + 6], s7 = sorted[e + 7];
      unsigned i0 = s0 & 0xFFFFu, i1 = s1 & 0xFFFFu, i2 = s2 & 0xFFFFu,
               i3 = s3 & 0xFFFFu, i4 = s4 & 0xFFFFu, i5 = s5 & 0xFFFFu,
               i6 = s6 & 0xFFFFu, i7 = s7 & 0xFFFFu;
      unsigned r0 = *(const unsigned*)(hb8 + ((size_t)i0 << 6) + (sl << 2));
      unsigned r1 = *(const unsigned*)(hb8 + ((size_t)i1 << 6) + (sl << 2));
      unsigned r2 = *(const unsigned*)(hb8 + ((size_t)i2 << 6) + (sl << 2));
      unsigned r3 = *(const unsigned*)(hb8 + ((size_t)i3 << 6) + (sl << 2));
      unsigned r4 = *(const unsigned*)(hb8 + ((size_t)i4 << 6) + (sl << 2));
      unsigned r5 = *(const unsigned*)(hb8 + ((size_t)i5 << 6) + (sl << 2));
      unsigned r6 = *(const unsigned*)(hb8 + ((size_t)i6 << 6) + (sl << 2));
      unsigned r7 = *(const unsigned*)(hb8 + ((size_t)i7 << 6) + (sl << 2));
      float n0 = dn * dinv[i0] * bhi(s0);
      float n1 = dn * dinv[i1] * bhi(s1);
      float n2 = dn * dinv[i2] * bhi(s2);
      float n3 = dn * dinv[i3] * bhi(s3);
      float n4 = dn * dinv[i4] * bhi(s4);
      float n5 = dn * dinv[i5] * bhi(s5);
      float n6 = dn * dinv[i6] * bhi(s6);
      float n7 = dn * dinv[i7] * bhi(s7);
      float4 f0 = dec8(r0), f1 = dec8(r1), f2 = dec8(r2), f3 = dec8(r3);
      float4 f4 = dec8(r4), f5 = dec8(r5), f6 = dec8(r6), f7 = dec8(r7);
      ax += n0 * f0.x + n1 * f1.x + n2 * f2.x + n3 * f3.x +
            n4 * f4.x + n5 * f5.x + n6 * f6.x + n7 * f7.x;
      ay += n0 * f0.y + n1 * f1.y + n2 * f2.y + n3 * f3.y +
            n4 * f4.y + n5 * f5.y + n6 * f6.y + n7 * f7.y;
      az += n0 * f0.z + n1 * f1.z + n2 * f2.z + n3 * f3.z +
            n4 * f4.z + n5 * f5.z + n6 * f6.z + n7 * f7.z;
      aw += n0 * f0.w + n1 * f1.w + n2 * f2.w + n3 * f3.w +
            n4 * f4.w + n5 * f5.w + n6 * f6.w + n7 * f7.w;
    }
    for (; e < end; ++e) {
      unsigned s0 = sorted[e];
      unsigned i0 = s0 & 0xFFFFu;
      unsigned r0 = *(const unsigned*)(hb8 + ((size_t)i0 << 6) + (sl << 2));
      float n0 = dn * dinv[i0] * bhi(s0);
      float4 f0 = dec8(r0);
      ax += n0 * f0.x;
      ay += n0 * f0.y;
      az += n0 * f0.z;
      aw += n0 * f0.w;
    }
    float4 fw = ((const float4*)fcw)[(size_t)n * 16 + sl];
    p = fmaxf(ax, 0.f) * fw.x + fmaxf(ay, 0.f) * fw.y +
        fmaxf(az, 0.f) * fw.z + fmaxf(aw, 0.f) * fw.w;
  }
  p += __shfl_down(p, 8);
  p += __shfl_down(p, 4);
  p += __shfl_down(p, 2);
  p += __shfl_down(p, 1);
  __shared__ float ls[16];
  if (sl == 0) ls[wid * 4 + seg] = p;
  __syncthreads();
  if (threadIdx.x == 0) {
    float s = 0.f;
#pragma unroll
    for (int i = 0; i < 16; ++i) s += ls[i];
    partials[blockIdx.x] = s;
  }
}

// ---------------- final: sum partials, + fc_b, sigmoid ----------------------
__global__ __launch_bounds__(1024) void k_fred(const float* __restrict__ partials,
                                               int M,
                                               const float* __restrict__ fcb,
                                               float* __restrict__ out) {
  const int t = threadIdx.x;
  float s = 0.0f;
  for (int i = t; i < M; i += 1024) s += partials[i];
#pragma unroll
  for (int off = 32; off > 0; off >>= 1) s += __shfl_down(s, off);
  __shared__ float ls[16];
  if ((t & 63) == 0) ls[t >> 6] = s;
  __syncthreads();
  if (t == 0) {
    float tot = 0.0f;
#pragma unroll
    for (int i = 0; i < 16; ++i) tot += ls[i];
    float logit = tot + fcb[0];
    out[0] = 1.0f / (1.0f + expf(-logit));
  }
}

extern "C" void kernel_launch(void* const* d_in, const int* in_sizes, int n_in,
                              void* d_out, int out_size, void* d_ws, size_t ws_size,
                              hipStream_t stream) {
  const float* x      = (const float*)d_in[0];
  const int*   elist  = (const int*)d_in[1];
  const float* eattr  = (const float*)d_in[2];
  const float* conv_w = (const float*)d_in[3];
  const float* conv_b = (const float*)d_in[4];
  const float* fc_w   = (const float*)d_in[5];
  const float* fc_b   = (const float*)d_in[6];
  float* out = (float*)d_out;

  const int N = in_sizes[0] / F;   // 50000
  const int E = in_sizes[2];       // 1,600,000
  const int* src = elist;
  const int* dst = elist + E;

  const int chsz = (E + NCH - 1) / NCH;        // 6250 (<= CHMAX)
  const int nbuk = ((N - 1) >> SHIFT) + 1;     // 391
  const int M = nbuk * NCH;                    // 100096
  const int nS = (M + 1023) / 1024;            // 98

  char* wsb = (char*)d_ws;
  unsigned* rec4 = (unsigned*)wsb;                             // E*4 (packed)
  unsigned* sorted = rec4 + E;                                 // E*4 (packed)
  unsigned* hb8 = sorted + E;                                  // N*64 B
  int*   counts = (int*)(hb8 + (size_t)N * 16);                // M*4
  int*   rawc   = counts + M;                                  // M*4
  int*   cnt    = rawc + M;                                    // N*4
  int*   cursor = cnt + N;                                     // N*4
  float* dinv   = (float*)(cursor + N);                        // N*4
  const int nAgg = (N + 15) / 16;
  float* partials = dinv + N;                                  // nAgg*4
  int*   bsum   = (int*)(partials + nAgg);                     // nS*4
  unsigned short* rank = (unsigned short*)(bsum + nS);         // E*2
  unsigned char* dl = (unsigned char*)(rank + E);              // E*1

  kA_hist<<<NCH, 1024, 0, stream>>>(dst, counts, rawc, rank, E, chsz, nbuk);
  kS1<<<nS, 1024, 0, stream>>>(counts, bsum, M);
  kS2<<<nS, 1024, 0, stream>>>(counts, bsum, M);
  kA_scat<<<NCH, 1024, 0, stream>>>(src, dst, eattr, rank, counts, rawc, rec4,
                                    dl, E, chsz, nbuk);
  kB_sort<<<nbuk, 1024, 0, stream>>>(rec4, dl, counts, sorted, cnt, cursor, dinv,
                                     E, nbuk, N);
  k_gemm<<<(N + NB - 1) / NB, 256, 0, stream>>>(x, conv_w, hb8, N);
  k_agg<<<nAgg, 256, 0, stream>>>(sorted, cursor, cnt, dinv,
                                  (const unsigned char*)hb8, conv_b, fc_w,
                                  partials, N);
  k_fred<<<1, 1024, 0, stream>>>(partials, nAgg, fc_b, out);
}